// Round 1
// baseline (2647.104 us; speedup 1.0000x reference)
//
#include <hip/hip_runtime.h>

#define B 16
#define C 256
#define H 32
#define W 32
#define HW (H * W)
#define T_STEPS 8
#define NGROUPS 64            // groups of 4 channels (N_OSC=4)
#define EPS_GN 1e-5f
#define EPS_NORM 1e-12f
#define N_ELEM ((size_t)B * C * HW)   // 4,194,304 elements per tensor

// ---------------- zero the energy region ----------------
__global__ void zero_es_kernel(float* es) {
    int i = threadIdx.x;
    if (i < (T_STEPS + 1) * B) es[i] = 0.0f;
}

// ---------------- GroupNorm(c) * gn_w + gn_b + conv_b -> c_hat ----------------
// one block per (b, group); group = 4 channels x 32x32 = 4096 contiguous floats
__global__ __launch_bounds__(256) void gn_kernel(
    const float* __restrict__ c, const float* __restrict__ gn_w,
    const float* __restrict__ gn_b, const float* __restrict__ conv_b,
    float* __restrict__ c_hat) {
    int blk = blockIdx.x;          // b*64 + g
    int b = blk >> 6, g = blk & 63;
    const float* src = c + ((size_t)(b * C + 4 * g)) * HW;
    float sum = 0.f, sq = 0.f;
    for (int i = threadIdx.x; i < 4 * HW; i += 256) {
        float v = src[i];
        sum += v; sq += v * v;
    }
    #pragma unroll
    for (int o = 32; o > 0; o >>= 1) {
        sum += __shfl_down(sum, o, 64);
        sq  += __shfl_down(sq, o, 64);
    }
    __shared__ float s1[4], s2[4];
    if ((threadIdx.x & 63) == 0) { s1[threadIdx.x >> 6] = sum; s2[threadIdx.x >> 6] = sq; }
    __syncthreads();
    sum = s1[0] + s1[1] + s1[2] + s1[3];
    sq  = s2[0] + s2[1] + s2[2] + s2[3];
    float mean = sum * (1.0f / (4 * HW));
    float var  = sq  * (1.0f / (4 * HW)) - mean * mean;
    float scale = rsqrtf(var + EPS_GN);
    float* dst = c_hat + ((size_t)(b * C + 4 * g)) * HW;
    for (int i = threadIdx.x; i < 4 * HW; i += 256) {
        int ch = 4 * g + (i >> 10);
        dst[i] = (src[i] - mean) * scale * gn_w[ch] + gn_b[ch] + conv_b[ch];
    }
}

// ---------------- initial x normalize over 4-osc groups ----------------
__global__ __launch_bounds__(256) void normx_kernel(
    const float* __restrict__ x, float* __restrict__ x0) {
    int gid = blockIdx.x * 256 + threadIdx.x;   // (b, g, hw)
    int b = gid >> 16;
    int rem = gid & 65535;
    int g = rem >> 10, hw = rem & 1023;
    size_t base = ((size_t)(b * C + 4 * g)) * HW + hw;
    float v0 = x[base], v1 = x[base + HW], v2 = x[base + 2 * HW], v3 = x[base + 3 * HW];
    float nrm = sqrtf(v0 * v0 + v1 * v1 + v2 * v2 + v3 * v3);
    float inv = 1.0f / fmaxf(nrm, EPS_NORM);
    x0[base] = v0 * inv; x0[base + HW] = v1 * inv;
    x0[base + 2 * HW] = v2 * inv; x0[base + 3 * HW] = v3 * inv;
}

// ---------------- direct 3x3 conv, y = conv(x) + c_hat (c_hat includes conv_b) ----
// grid: B * (C/8) blocks; each block: (b, 8 output channels, full 32x32 plane)
// x plane staged in LDS with zero halo; weights via wave-uniform (scalar) loads.
#define CO_PER_BLK 8
__global__ __launch_bounds__(256) void conv_kernel(
    const float* __restrict__ x, const float* __restrict__ cw,
    const float* __restrict__ c_hat, float* __restrict__ y) {
    __shared__ float plane[34 * 34];
    int b = blockIdx.x >> 5;
    int co_base = (blockIdx.x & 31) * CO_PER_BLK;
    int tid = threadIdx.x;
    for (int i = tid; i < 34 * 34; i += 256) plane[i] = 0.0f;  // zero halo (stays 0)

    float acc[CO_PER_BLK][4];
    #pragma unroll
    for (int co = 0; co < CO_PER_BLK; co++)
        #pragma unroll
        for (int r = 0; r < 4; r++) acc[co][r] = 0.f;

    int wcol = tid & 31;          // output col
    int hgrp = tid >> 5;          // 0..7 -> output rows 4*hgrp..4*hgrp+3
    int h0 = hgrp * 4;
    int sh = tid >> 3;            // staging row 0..31
    int sw = (tid & 7) * 4;       // staging col
    __syncthreads();

    for (int ci = 0; ci < C; ci++) {
        // stage x[b][ci] plane into LDS interior
        const float4 v = *reinterpret_cast<const float4*>(
            x + ((size_t)(b * C + ci)) * HW + tid * 4);
        float* p = plane + (sh + 1) * 34 + sw + 1;
        p[0] = v.x; p[1] = v.y; p[2] = v.z; p[3] = v.w;
        __syncthreads();

        // 6 rows x 3 cols neighborhood for 4 output rows
        float xv[6][3];
        #pragma unroll
        for (int r = 0; r < 6; r++)
            #pragma unroll
            for (int dc = 0; dc < 3; dc++)
                xv[r][dc] = plane[(h0 + r) * 34 + wcol + dc];

        const float* wp = cw + (((size_t)co_base * C) + ci) * 9;  // wave-uniform
        #pragma unroll
        for (int co = 0; co < CO_PER_BLK; co++) {
            float wg[9];
            #pragma unroll
            for (int j = 0; j < 9; j++) wg[j] = wp[(size_t)co * C * 9 + j];
            #pragma unroll
            for (int r = 0; r < 4; r++)
                #pragma unroll
                for (int kh = 0; kh < 3; kh++)
                    #pragma unroll
                    for (int kw = 0; kw < 3; kw++)
                        acc[co][r] += xv[r + kh][kw] * wg[kh * 3 + kw];
        }
        __syncthreads();
    }

    #pragma unroll
    for (int co = 0; co < CO_PER_BLK; co++) {
        #pragma unroll
        for (int r = 0; r < 4; r++) {
            size_t idx = ((size_t)(b * C + co_base + co)) * HW + (h0 + r) * W + wcol;
            y[idx] = acc[co][r] + c_hat[idx];
        }
    }
}

// ---------------- fused oscillator update ----------------
// thread per (b, g, hw): sim, energy, omega rotation, dxdt, renormalize
__global__ __launch_bounds__(256) void update_kernel(
    const float* __restrict__ x_prev, const float* __restrict__ y,
    const float* __restrict__ omg_param, const float* __restrict__ gamma_p,
    float* __restrict__ x_out, float* __restrict__ es_t) {
    int gid = blockIdx.x * 256 + threadIdx.x;
    int b = gid >> 16;
    int rem = gid & 65535;
    int g = rem >> 10, hw = rem & 1023;
    size_t base = ((size_t)(b * C + 4 * g)) * HW + hw;

    float x0 = x_prev[base], x1 = x_prev[base + HW];
    float x2 = x_prev[base + 2 * HW], x3 = x_prev[base + 3 * HW];
    float y0 = y[base], y1 = y[base + HW];
    float y2 = y[base + 2 * HW], y3 = y[base + 3 * HW];

    float s = x0 * y0 + x1 * y1 + x2 * y2 + x3 * y3;

    // omega: pairs (2g, 2g+1) of omg_param rows
    float a0 = omg_param[4 * g + 0], a1 = omg_param[4 * g + 1];
    float a2 = omg_param[4 * g + 2], a3 = omg_param[4 * g + 3];
    float o0 = sqrtf(a0 * a0 + a1 * a1);
    float o1 = sqrtf(a2 * a2 + a3 * a3);

    float gam = gamma_p[0];
    float d0 =  o0 * x1 + y0 - s * x0;
    float d1 = -o0 * x0 + y1 - s * x1;
    float d2 =  o1 * x3 + y2 - s * x2;
    float d3 = -o1 * x2 + y3 - s * x3;

    float n0 = x0 + gam * d0, n1 = x1 + gam * d1;
    float n2 = x2 + gam * d2, n3 = x3 + gam * d3;
    float nrm = sqrtf(n0 * n0 + n1 * n1 + n2 * n2 + n3 * n3);
    float inv = 1.0f / fmaxf(nrm, EPS_NORM);
    x_out[base] = n0 * inv; x_out[base + HW] = n1 * inv;
    x_out[base + 2 * HW] = n2 * inv; x_out[base + 3 * HW] = n3 * inv;

    // energy: sum of -sim over everything per batch
    float e = -s;
    #pragma unroll
    for (int o = 32; o > 0; o >>= 1) e += __shfl_down(e, o, 64);
    __shared__ float red[4];
    if ((threadIdx.x & 63) == 0) red[threadIdx.x >> 6] = e;
    __syncthreads();
    if (threadIdx.x == 0)
        atomicAdd(es_t + b, red[0] + red[1] + red[2] + red[3]);
}

extern "C" void kernel_launch(void* const* d_in, const int* in_sizes, int n_in,
                              void* d_out, int out_size, void* d_ws, size_t ws_size,
                              hipStream_t stream) {
    const float* x        = (const float*)d_in[0];
    const float* c        = (const float*)d_in[1];
    // d_in[2] = T (int scalar, known = 8)
    const float* gamma_p  = (const float*)d_in[3];
    const float* conv_w   = (const float*)d_in[4];
    const float* conv_b   = (const float*)d_in[5];
    const float* gn_w     = (const float*)d_in[6];
    const float* gn_b     = (const float*)d_in[7];
    const float* omg_par  = (const float*)d_in[8];

    float* out = (float*)d_out;
    float* es  = out + (size_t)T_STEPS * N_ELEM;   // (T+1, B) region

    float* ws    = (float*)d_ws;
    float* c_hat = ws;                 // N_ELEM floats
    float* x0    = ws + N_ELEM;        // N_ELEM floats
    float* ybuf  = ws + 2 * N_ELEM;    // N_ELEM floats

    zero_es_kernel<<<1, 256, 0, stream>>>(es);
    gn_kernel<<<B * NGROUPS, 256, 0, stream>>>(c, gn_w, gn_b, conv_b, c_hat);
    normx_kernel<<<(B * NGROUPS * HW) / 256, 256, 0, stream>>>(x, x0);

    const float* xp = x0;
    for (int t = 0; t < T_STEPS; t++) {
        conv_kernel<<<B * (C / CO_PER_BLK), 256, 0, stream>>>(xp, conv_w, c_hat, ybuf);
        float* xs_t = out + (size_t)t * N_ELEM;
        update_kernel<<<(B * NGROUPS * HW) / 256, 256, 0, stream>>>(
            xp, ybuf, omg_par, gamma_p, xs_t, es + (size_t)(t + 1) * B);
        xp = xs_t;
    }
}

// Round 2
// 328.892 us; speedup vs baseline: 8.0485x; 8.0485x over previous
//
#include <hip/hip_runtime.h>

typedef _Float16 f16;
typedef _Float16 f16x8 __attribute__((ext_vector_type(8)));
typedef float f32x4 __attribute__((ext_vector_type(4)));

#define B 16
#define C 256
#define H 32
#define W 32
#define HW (H * W)
#define T_STEPS 8
#define NGROUPS 64
#define EPS_GN 1e-5f
#define EPS_NORM 1e-12f
#define N_ELEM ((size_t)B * C * HW)

// ---------------- zero the energy region ----------------
__global__ void zero_es_kernel(float* es) {
    int i = threadIdx.x;
    if (i < (T_STEPS + 1) * B) es[i] = 0.0f;
}

// ---------------- GroupNorm(c) * gn_w + gn_b + conv_b -> c_hat (f32) --------
__global__ __launch_bounds__(256) void gn_kernel(
    const float* __restrict__ c, const float* __restrict__ gn_w,
    const float* __restrict__ gn_b, const float* __restrict__ conv_b,
    float* __restrict__ c_hat) {
    int blk = blockIdx.x;          // b*64 + g
    int b = blk >> 6, g = blk & 63;
    const float* src = c + ((size_t)(b * C + 4 * g)) * HW;
    float sum = 0.f, sq = 0.f;
    for (int i = threadIdx.x; i < 4 * HW; i += 256) {
        float v = src[i];
        sum += v; sq += v * v;
    }
    #pragma unroll
    for (int o = 32; o > 0; o >>= 1) {
        sum += __shfl_down(sum, o, 64);
        sq  += __shfl_down(sq, o, 64);
    }
    __shared__ float s1[4], s2[4];
    if ((threadIdx.x & 63) == 0) { s1[threadIdx.x >> 6] = sum; s2[threadIdx.x >> 6] = sq; }
    __syncthreads();
    sum = s1[0] + s1[1] + s1[2] + s1[3];
    sq  = s2[0] + s2[1] + s2[2] + s2[3];
    float mean = sum * (1.0f / (4 * HW));
    float var  = sq  * (1.0f / (4 * HW)) - mean * mean;
    float scale = rsqrtf(var + EPS_GN);
    float* dst = c_hat + ((size_t)(b * C + 4 * g)) * HW;
    for (int i = threadIdx.x; i < 4 * HW; i += 256) {
        int ch = 4 * g + (i >> 10);
        dst[i] = (src[i] - mean) * scale * gn_w[ch] + gn_b[ch] + conv_b[ch];
    }
}

// ---------------- initial x normalize: writes f32 x0 AND f16 copy ----------
__global__ __launch_bounds__(256) void normx_kernel(
    const float* __restrict__ x, float* __restrict__ x0, f16* __restrict__ xh) {
    int gid = blockIdx.x * 256 + threadIdx.x;   // (b, g, hw)
    int b = gid >> 16;
    int rem = gid & 65535;
    int g = rem >> 10, hw = rem & 1023;
    size_t base = ((size_t)(b * C + 4 * g)) * HW + hw;
    float v0 = x[base], v1 = x[base + HW], v2 = x[base + 2 * HW], v3 = x[base + 3 * HW];
    float nrm = sqrtf(v0 * v0 + v1 * v1 + v2 * v2 + v3 * v3);
    float inv = 1.0f / fmaxf(nrm, EPS_NORM);
    v0 *= inv; v1 *= inv; v2 *= inv; v3 *= inv;
    x0[base] = v0; x0[base + HW] = v1; x0[base + 2 * HW] = v2; x0[base + 3 * HW] = v3;
    xh[base] = (f16)v0; xh[base + HW] = (f16)v1;
    xh[base + 2 * HW] = (f16)v2; xh[base + 3 * HW] = (f16)v3;
}

// ---------------- weight convert: conv_w [co][ci][3][3] f32 -> wh [khkw][co][ci] f16
__global__ __launch_bounds__(256) void wconvert_kernel(
    const float* __restrict__ cw, f16* __restrict__ wh) {
    int idx = blockIdx.x * 256 + threadIdx.x;   // khkw*65536 + co*256 + ci
    int ci = idx & 255;
    int co = (idx >> 8) & 255;
    int khkw = idx >> 16;
    wh[idx] = (f16)cw[((size_t)(co * C + ci)) * 9 + khkw];
}

// ---------------- fused MFMA conv + oscillator update ----------------------
// block: b fixed, 64 output channels (cotile), 128 pixels (4 rows x 32 cols).
// 4 waves as 2x2: wave tile = 32 co x 64 pixels. K = 8 ci-chunks x 9 khkw x 32.
// Epilogue: y = acc + c_hat, then sim/omega/dxdt/renormalize per osc group
// (the 4 D-regs of a fragment are exactly one group's 4 channels).
__global__ __launch_bounds__(256, 2) void conv_update_kernel(
    const f16* __restrict__ xh, const f16* __restrict__ wh,
    const float* __restrict__ c_hat, const float* __restrict__ x_prev,
    const float* __restrict__ omg, const float* __restrict__ gamma_p,
    float* __restrict__ xs_out, f16* __restrict__ xh_out,
    float* __restrict__ es_b) {
    __shared__ __align__(16) f16 Xs[6][34][40];   // [row -1..4][col -1..32][ci], pad 40
    __shared__ __align__(16) f16 Ws[9][64][40];   // [khkw][co][ci], pad 40
    __shared__ float red[4];

    const int bid = blockIdx.x;
    const int b = bid >> 5;
    const int cotile = (bid >> 3) & 3;   // *64 channels
    const int rowtile = bid & 7;         // *4 rows
    const int h0 = rowtile * 4;
    const int tid = threadIdx.x;
    const int lane = tid & 63;
    const int wv = tid >> 6;
    const int wave_m = wv >> 1;          // 0..1 -> co offset *32
    const int wave_n = wv & 1;           // 0..1 -> pixel offset *64
    const int n16 = lane & 15;
    const int grp = lane >> 4;           // k-group 0..3

    // zero Xs once: halo cells (image border rows/cols) must stay 0 across chunks
    {
        float4* p = reinterpret_cast<float4*>(&Xs[0][0][0]);
        for (int i = tid; i < (6 * 34 * 40 * 2) / 16; i += 256)
            p[i] = float4{0.f, 0.f, 0.f, 0.f};
    }

    f32x4 acc[2][4];
    #pragma unroll
    for (int i = 0; i < 2; i++)
        #pragma unroll
        for (int j = 0; j < 4; j++) acc[i][j] = {0.f, 0.f, 0.f, 0.f};

    for (int cb = 0; cb < C; cb += 32) {
        __syncthreads();
        // stage W chunk: Ws[khkw][co 0..63][ci 0..31]
        #pragma unroll
        for (int s = 0; s < 9; s++) {
            int L = tid + 256 * s;              // 0..2303
            int quad = L & 3;
            int co = (L >> 2) & 63;
            int khkw = L >> 8;
            f16x8 v = *reinterpret_cast<const f16x8*>(
                wh + ((size_t)(khkw * C + cotile * 64 + co)) * C + cb + quad * 8);
            *reinterpret_cast<f16x8*>(&Ws[khkw][co][quad * 8]) = v;
        }
        // stage X chunk: Xs[r][1+col][ci]; r=0..5 <-> image row h0-1+r
        #pragma unroll
        for (int s = 0; s < 3; s++) {
            int L = tid + 256 * s;              // 0..767
            int ci = L & 31;
            int rc = L >> 5;                    // 0..23
            int r = rc >> 2;
            int c8 = rc & 3;
            int row = h0 - 1 + r;
            if ((unsigned)row < 32u) {
                f16x8 v = *reinterpret_cast<const f16x8*>(
                    xh + ((size_t)(b * C + cb + ci)) * HW + row * W + c8 * 8);
                #pragma unroll
                for (int k = 0; k < 8; k++) Xs[r][c8 * 8 + k + 1][ci] = v[k];
            }
        }
        __syncthreads();

        #pragma unroll
        for (int khkw = 0; khkw < 9; khkw++) {
            const int kh = khkw / 3, kw = khkw % 3;
            f16x8 a0 = *reinterpret_cast<const f16x8*>(
                &Ws[khkw][wave_m * 32 + n16][grp * 8]);
            f16x8 a1 = *reinterpret_cast<const f16x8*>(
                &Ws[khkw][wave_m * 32 + 16 + n16][grp * 8]);
            f16x8 bf[4];
            #pragma unroll
            for (int nt = 0; nt < 4; nt++) {
                int pixb = wave_n * 64 + nt * 16;
                bf[nt] = *reinterpret_cast<const f16x8*>(
                    &Xs[(pixb >> 5) + kh][(pixb & 31) + n16 + kw][grp * 8]);
            }
            #pragma unroll
            for (int nt = 0; nt < 4; nt++) {
                acc[0][nt] = __builtin_amdgcn_mfma_f32_16x16x32_f16(
                    a0, bf[nt], acc[0][nt], 0, 0, 0);
                acc[1][nt] = __builtin_amdgcn_mfma_f32_16x16x32_f16(
                    a1, bf[nt], acc[1][nt], 0, 0, 0);
            }
        }
    }

    // ---------------- epilogue: fused oscillator update ----------------
    const float gam = gamma_p[0];
    float e = 0.0f;
    #pragma unroll
    for (int mt = 0; mt < 2; mt++) {
        // D-frag: row(co) = grp*4 + reg, col(pix) = n16  [m89-verified layout]
        const int co0 = cotile * 64 + wave_m * 32 + mt * 16 + grp * 4; // %4==0
        const float a0 = omg[co0], a1 = omg[co0 + 1];
        const float a2 = omg[co0 + 2], a3 = omg[co0 + 3];
        const float o0 = sqrtf(a0 * a0 + a1 * a1);
        const float o1 = sqrtf(a2 * a2 + a3 * a3);
        #pragma unroll
        for (int nt = 0; nt < 4; nt++) {
            int pix = wave_n * 64 + nt * 16 + n16;       // 0..127
            size_t base = ((size_t)(b * C + co0)) * HW + h0 * W + pix;
            float y0 = acc[mt][nt][0] + c_hat[base];
            float y1 = acc[mt][nt][1] + c_hat[base + HW];
            float y2 = acc[mt][nt][2] + c_hat[base + 2 * HW];
            float y3 = acc[mt][nt][3] + c_hat[base + 3 * HW];
            float x0 = x_prev[base],        x1 = x_prev[base + HW];
            float x2 = x_prev[base + 2*HW], x3 = x_prev[base + 3*HW];
            float s = x0 * y0 + x1 * y1 + x2 * y2 + x3 * y3;
            float d0 =  o0 * x1 + y0 - s * x0;
            float d1 = -o0 * x0 + y1 - s * x1;
            float d2 =  o1 * x3 + y2 - s * x2;
            float d3 = -o1 * x2 + y3 - s * x3;
            float n0 = x0 + gam * d0, n1 = x1 + gam * d1;
            float n2 = x2 + gam * d2, n3 = x3 + gam * d3;
            float nrm = sqrtf(n0 * n0 + n1 * n1 + n2 * n2 + n3 * n3);
            float inv = 1.0f / fmaxf(nrm, EPS_NORM);
            n0 *= inv; n1 *= inv; n2 *= inv; n3 *= inv;
            xs_out[base]          = n0; xs_out[base + HW]     = n1;
            xs_out[base + 2 * HW] = n2; xs_out[base + 3 * HW] = n3;
            xh_out[base]          = (f16)n0; xh_out[base + HW]     = (f16)n1;
            xh_out[base + 2 * HW] = (f16)n2; xh_out[base + 3 * HW] = (f16)n3;
            e -= s;
        }
    }
    #pragma unroll
    for (int o = 32; o > 0; o >>= 1) e += __shfl_down(e, o, 64);
    if (lane == 0) red[wv] = e;
    __syncthreads();
    if (tid == 0) atomicAdd(es_b + b, red[0] + red[1] + red[2] + red[3]);
}

extern "C" void kernel_launch(void* const* d_in, const int* in_sizes, int n_in,
                              void* d_out, int out_size, void* d_ws, size_t ws_size,
                              hipStream_t stream) {
    const float* x        = (const float*)d_in[0];
    const float* c        = (const float*)d_in[1];
    // d_in[2] = T (int scalar, known = 8)
    const float* gamma_p  = (const float*)d_in[3];
    const float* conv_w   = (const float*)d_in[4];
    const float* conv_b   = (const float*)d_in[5];
    const float* gn_w     = (const float*)d_in[6];
    const float* gn_b     = (const float*)d_in[7];
    const float* omg_par  = (const float*)d_in[8];

    float* out = (float*)d_out;
    float* es  = out + (size_t)T_STEPS * N_ELEM;   // (T+1, B) region

    // workspace: c_hat f32 (16MB) | xh0 f16 (8MB) | xh1 f16 (8MB) | wh f16 (1.2MB)
    float* c_hat = (float*)d_ws;
    f16* xh0 = (f16*)(c_hat + N_ELEM);
    f16* xh1 = xh0 + N_ELEM;
    f16* wh  = xh1 + N_ELEM;
    // f32 x0 lives in the xs[7] slot of d_out (overwritten at t=7, after last use)
    float* x0f = out + (size_t)(T_STEPS - 1) * N_ELEM;

    zero_es_kernel<<<1, 256, 0, stream>>>(es);
    gn_kernel<<<B * NGROUPS, 256, 0, stream>>>(c, gn_w, gn_b, conv_b, c_hat);
    normx_kernel<<<(B * NGROUPS * HW) / 256, 256, 0, stream>>>(x, x0f, xh0);
    wconvert_kernel<<<(9 * C * C) / 256, 256, 0, stream>>>(conv_w, wh);

    f16* xh_bufs[2] = {xh0, xh1};
    const float* xp = x0f;
    for (int t = 0; t < T_STEPS; t++) {
        float* xs_t = out + (size_t)t * N_ELEM;
        conv_update_kernel<<<512, 256, 0, stream>>>(
            xh_bufs[t & 1], wh, c_hat, xp, omg_par, gamma_p,
            xs_t, xh_bufs[(t + 1) & 1], es + (size_t)(t + 1) * B);
        xp = xs_t;
    }
}